// Round 1
// baseline (495.881 us; speedup 1.0000x reference)
//
#include <hip/hip_runtime.h>

#define C_IN 64
#define C_OUT 16
#define H_IN 256
#define W_IN 256
#define HP 258
#define WP 258
#define N_B 8
#define L4 4096
#define L8 3969
#define L12 3844
#define LTOT 11909   // 4096 + 3969 + 3844

// ---------------------------------------------------------------------------
// Stage 1: edge-pad + 1x1 conv 64->16.
// y[((n*16 + o)*258 + h)*258 + w] = sum_c x[n][c][clamp(h-1)][clamp(w-1)] * W[o][c] + b[o]
// One block per (n, h) row; threads stride over w. Channel loads are coalesced
// (consecutive lanes -> consecutive w). Weights are wave-uniform -> s_load.
// ---------------------------------------------------------------------------
__global__ __launch_bounds__(256) void reduce_kernel(
    const float* __restrict__ x, const float* __restrict__ w,
    const float* __restrict__ b, float* __restrict__ y) {
  const int row = blockIdx.x;            // 0 .. N_B*HP-1
  const int n = row / HP;
  const int h = row - n * HP;
  const int hs = min(max(h - 1, 0), H_IN - 1);

  for (int wp = threadIdx.x; wp < WP; wp += blockDim.x) {
    const int wsrc = min(max(wp - 1, 0), W_IN - 1);
    float acc[C_OUT];
#pragma unroll
    for (int o = 0; o < C_OUT; ++o) acc[o] = b[o];
    const float* xp = x + (size_t)n * C_IN * H_IN * W_IN + (size_t)hs * W_IN + wsrc;
#pragma unroll
    for (int c = 0; c < C_IN; ++c) {
      const float xv = xp[(size_t)c * (H_IN * W_IN)];
#pragma unroll
      for (int o = 0; o < C_OUT; ++o) acc[o] = fmaf(xv, w[o * C_IN + c], acc[o]);
    }
    float* yp = y + ((size_t)(n * C_OUT) * HP + h) * WP + wp;
#pragma unroll
    for (int o = 0; o < C_OUT; ++o) yp[(size_t)o * (HP * WP)] = acc[o];
  }
}

// ---------------------------------------------------------------------------
// Stage 2a: k=4 patches, bilinear 4x4 -> 8x8 (jax.image.resize 'bilinear',
// half-pixel centers, edge-renormalized). For output index t in [0,8):
//   i0 = max(0,(t-1)>>1), i1 = min(3,(t+1)>>1),
//   w0 = 1 (t==0 or 7) else 0.75 (t odd) else 0.25.
// out[n][l][c][p][q], l = oh*64+ow, patch top-left = (oh*4, ow*4) in y.
// ---------------------------------------------------------------------------
__global__ __launch_bounds__(256) void patch4_kernel(
    const float* __restrict__ y, float* __restrict__ out) {
  const int idx = blockIdx.x * 256 + threadIdx.x;   // exactly 8*4096*16*64
  const int q = idx & 7;
  const int p = (idx >> 3) & 7;
  const int c = (idx >> 6) & 15;
  const int l = (idx >> 10) & 4095;
  const int n = idx >> 22;
  const int ow = l & 63, oh = l >> 6;

  const int ip0 = max(0, (p - 1) >> 1), ip1 = min(3, (p + 1) >> 1);
  const int jq0 = max(0, (q - 1) >> 1), jq1 = min(3, (q + 1) >> 1);
  const float wp0 = (p == 0 || p == 7) ? 1.0f : ((p & 1) ? 0.75f : 0.25f);
  const float wq0 = (q == 0 || q == 7) ? 1.0f : ((q & 1) ? 0.75f : 0.25f);

  const float* yb = y + ((size_t)(n * C_OUT + c) * HP + oh * 4) * WP + ow * 4;
  const float v00 = yb[ip0 * WP + jq0], v01 = yb[ip0 * WP + jq1];
  const float v10 = yb[ip1 * WP + jq0], v11 = yb[ip1 * WP + jq1];
  const float vt = wq0 * v00 + (1.0f - wq0) * v01;
  const float vb = wq0 * v10 + (1.0f - wq0) * v11;
  const float v = wp0 * vt + (1.0f - wp0) * vb;

  out[((size_t)(n * LTOT + l) * C_OUT + c) * 64 + p * 8 + q] = v;
}

// ---------------------------------------------------------------------------
// Stage 2b: k=8 patches, identity copy. l = oh*63+ow.
// ---------------------------------------------------------------------------
__global__ __launch_bounds__(256) void patch8_kernel(
    const float* __restrict__ y, float* __restrict__ out) {
  const int idx = blockIdx.x * 256 + threadIdx.x;   // exactly 8*3969*16*64
  const int q = idx & 7;
  const int p = (idx >> 3) & 7;
  const int c = (idx >> 6) & 15;
  const int rest = idx >> 10;        // n*L8 + l
  const int n = rest / L8;
  const int l = rest - n * L8;
  const int ow = l % 63, oh = l / 63;

  const float v = y[((size_t)(n * C_OUT + c) * HP + oh * 4 + p) * WP + ow * 4 + q];
  out[((size_t)(n * LTOT + L4 + l) * C_OUT + c) * 64 + p * 8 + q] = v;
}

// ---------------------------------------------------------------------------
// Stage 2c: k=12 patches, adaptive avg 12 -> 8: output t averages inputs
// a..a+1 with a = (3*t)>>1  (pairs (0,1),(1,2),(3,4),(4,5),(6,7),(7,8),
// (9,10),(10,11)). 2-D: mean of 4. l = oh*62+ow.
// ---------------------------------------------------------------------------
__global__ __launch_bounds__(256) void patch12_kernel(
    const float* __restrict__ y, float* __restrict__ out) {
  const int idx = blockIdx.x * 256 + threadIdx.x;   // exactly 8*3844*16*64
  const int q = idx & 7;
  const int p = (idx >> 3) & 7;
  const int c = (idx >> 6) & 15;
  const int rest = idx >> 10;        // n*L12 + l
  const int n = rest / L12;
  const int l = rest - n * L12;
  const int ow = l % 62, oh = l / 62;

  const int A = oh * 4 + ((3 * p) >> 1);
  const int B = ow * 4 + ((3 * q) >> 1);
  const float* yb = y + ((size_t)(n * C_OUT + c) * HP + A) * WP + B;
  const float v = 0.25f * (yb[0] + yb[1] + yb[WP] + yb[WP + 1]);

  out[((size_t)(n * LTOT + L4 + L8 + l) * C_OUT + c) * 64 + p * 8 + q] = v;
}

extern "C" void kernel_launch(void* const* d_in, const int* in_sizes, int n_in,
                              void* d_out, int out_size, void* d_ws, size_t ws_size,
                              hipStream_t stream) {
  const float* x = (const float*)d_in[0];
  const float* w = (const float*)d_in[1];
  const float* b = (const float*)d_in[2];
  float* out = (float*)d_out;
  float* y = (float*)d_ws;   // 8*16*258*258 floats = 34.1 MB

  // Stage 1: 8*258 = 2064 row-blocks
  reduce_kernel<<<N_B * HP, 256, 0, stream>>>(x, w, b, y);

  // Stage 2: one thread per output element, exact grids (all divisible by 256)
  patch4_kernel<<<(N_B * L4 * C_OUT * 64) / 256, 256, 0, stream>>>(y, out);
  patch8_kernel<<<(N_B * L8 * C_OUT * 64) / 256, 256, 0, stream>>>(y, out);
  patch12_kernel<<<(N_B * L12 * C_OUT * 64) / 256, 256, 0, stream>>>(y, out);
}

// Round 2
// 245.736 us; speedup vs baseline: 2.0179x; 2.0179x over previous
//
#include <hip/hip_runtime.h>

#define C_IN 64
#define C_OUT 16
#define H 256
#define W 256
#define HW 65536      // 256*256
#define N_B 8
#define L4 4096
#define L8 3969
#define L12 3844
#define LTOT 11909    // 4096 + 3969 + 3844

// 4-byte-aligned float4 for the unaligned (ws0 % 4 == 3) row loads
typedef float float4u __attribute__((ext_vector_type(4), aligned(4)));

__device__ __forceinline__ float4 load4c(const float* __restrict__ row, int ws0) {
  if (ws0 >= 0) {
    float4u t = *reinterpret_cast<const float4u*>(row + ws0);
    return make_float4(t.x, t.y, t.z, t.w);
  }
  // ws0 == -1: padded cols {-1,0,1,2} -> clamp -1 -> 0
  return make_float4(row[0], row[0], row[1], row[2]);
}

__device__ __forceinline__ float4 load4u(const float* __restrict__ row, int off) {
  float4u t = *reinterpret_cast<const float4u*>(row + off);
  return make_float4(t.x, t.y, t.z, t.w);
}

// ---------------------------------------------------------------------------
// Stage 1: 1x1 conv 64->16 over the UNPADDED image (padding is done by
// coordinate clamping in the patch kernels, since 1x1 conv commutes with it).
// Skinny GEMM: each thread = 4 contiguous pixels x 16 outputs (64 fp32 acc).
// Weights transposed into LDS once (4 KB); read back as broadcast b128.
// ---------------------------------------------------------------------------
__global__ __launch_bounds__(256) void reduce_kernel(
    const float* __restrict__ x, const float* __restrict__ w,
    const float* __restrict__ b, float* __restrict__ y) {
  __shared__ float wt[C_IN][C_OUT];   // wt[c][o]
  for (int i = threadIdx.x; i < C_IN * C_OUT; i += 256)
    wt[i & 63][i >> 6] = w[i];        // w flat = o*64 + c
  __syncthreads();

  const unsigned gid = blockIdx.x * 256 + threadIdx.x;  // 131072 total
  const int n = gid >> 14;                // 16384 groups of 4 pixels per image
  const int pix = (gid & 16383) << 2;
  const float* xp = x + (size_t)n * C_IN * HW + pix;

  float4 acc[C_OUT];
#pragma unroll
  for (int o = 0; o < C_OUT; ++o) {
    const float bv = b[o];
    acc[o] = make_float4(bv, bv, bv, bv);
  }

#define FMA4(A, WS) \
  A.x = fmaf(xv.x, WS, A.x); A.y = fmaf(xv.y, WS, A.y); \
  A.z = fmaf(xv.z, WS, A.z); A.w = fmaf(xv.w, WS, A.w);

#pragma unroll
  for (int c = 0; c < C_IN; ++c) {
    const float4 xv = *reinterpret_cast<const float4*>(xp + (size_t)c * HW);
    const float4 w0 = *reinterpret_cast<const float4*>(&wt[c][0]);
    const float4 w1 = *reinterpret_cast<const float4*>(&wt[c][4]);
    const float4 w2 = *reinterpret_cast<const float4*>(&wt[c][8]);
    const float4 w3 = *reinterpret_cast<const float4*>(&wt[c][12]);
    FMA4(acc[0], w0.x)  FMA4(acc[1], w0.y)  FMA4(acc[2], w0.z)  FMA4(acc[3], w0.w)
    FMA4(acc[4], w1.x)  FMA4(acc[5], w1.y)  FMA4(acc[6], w1.z)  FMA4(acc[7], w1.w)
    FMA4(acc[8], w2.x)  FMA4(acc[9], w2.y)  FMA4(acc[10], w2.z) FMA4(acc[11], w2.w)
    FMA4(acc[12], w3.x) FMA4(acc[13], w3.y) FMA4(acc[14], w3.z) FMA4(acc[15], w3.w)
  }
#undef FMA4

  float* yp = y + (size_t)n * C_OUT * HW + pix;
#pragma unroll
  for (int o = 0; o < C_OUT; ++o)
    *reinterpret_cast<float4*>(yp + (size_t)o * HW) = acc[o];
}

// ---------------------------------------------------------------------------
// Stage 2a: k=4 patches, bilinear 4x4 -> 8x8. One thread = full 8-wide q row.
// Padded coords: patch row ip -> y row clamp(oh*4+ip-1), col j -> clamp(ow*4+j-1).
// ---------------------------------------------------------------------------
__global__ __launch_bounds__(256) void patch4_kernel(
    const float* __restrict__ y, float* __restrict__ out) {
  const unsigned idx = blockIdx.x * 256 + threadIdx.x;  // 4,194,304
  const int p = idx & 7;
  const int c = (idx >> 3) & 15;
  const int l = (idx >> 7) & 4095;
  const int n = idx >> 19;
  const int ow = l & 63, oh = l >> 6;

  const int ip0 = max(0, (p - 1) >> 1), ip1 = min(3, (p + 1) >> 1);
  const float wp0 = (p == 0 || p == 7) ? 1.0f : ((p & 1) ? 0.75f : 0.25f);

  const int r0 = min(max(oh * 4 + ip0 - 1, 0), H - 1);
  const int r1 = min(max(oh * 4 + ip1 - 1, 0), H - 1);
  const int ws0 = ow * 4 - 1;
  const float* yb = y + (size_t)(n * C_OUT + c) * HW;
  const float4 va = load4c(yb + (size_t)r0 * W, ws0);
  const float4 vb = load4c(yb + (size_t)r1 * W, ws0);
  const float ra[4] = {va.x, va.y, va.z, va.w};
  const float rb[4] = {vb.x, vb.y, vb.z, vb.w};

  const int jq0[8] = {0, 0, 0, 1, 1, 2, 2, 3};
  const int jq1[8] = {0, 1, 1, 2, 2, 3, 3, 3};
  const float wq0[8] = {1.f, .75f, .25f, .75f, .25f, .75f, .25f, 1.f};

  float v[8];
#pragma unroll
  for (int q = 0; q < 8; ++q) {
    const float top = wq0[q] * ra[jq0[q]] + (1.0f - wq0[q]) * ra[jq1[q]];
    const float bot = wq0[q] * rb[jq0[q]] + (1.0f - wq0[q]) * rb[jq1[q]];
    v[q] = wp0 * top + (1.0f - wp0) * bot;
  }

  float* op = out + ((size_t)(n * LTOT + l) * C_OUT + c) * 64 + p * 8;
  *reinterpret_cast<float4*>(op) = make_float4(v[0], v[1], v[2], v[3]);
  *reinterpret_cast<float4*>(op + 4) = make_float4(v[4], v[5], v[6], v[7]);
}

// ---------------------------------------------------------------------------
// Stage 2b: k=8 patches, identity copy. One thread = full 8-wide q row.
// ---------------------------------------------------------------------------
__global__ __launch_bounds__(256) void patch8_kernel(
    const float* __restrict__ y, float* __restrict__ out) {
  const unsigned idx = blockIdx.x * 256 + threadIdx.x;  // 4,064,256
  const int p = idx & 7;
  const int c = (idx >> 3) & 15;
  const unsigned rest = idx >> 7;       // n*L8 + l
  const int n = rest / L8;
  const int l = rest - n * L8;
  const int ow = l % 63, oh = l / 63;

  const int r = min(max(oh * 4 + p - 1, 0), H - 1);
  const int ws0 = ow * 4 - 1;
  const float* yrow = y + (size_t)(n * C_OUT + c) * HW + (size_t)r * W;
  const float4 v0 = load4c(yrow, ws0);
  const float4 v1 = load4u(yrow, ws0 + 4);

  float* op = out + ((size_t)(n * LTOT + L4 + l) * C_OUT + c) * 64 + p * 8;
  *reinterpret_cast<float4*>(op) = v0;
  *reinterpret_cast<float4*>(op + 4) = v1;
}

// ---------------------------------------------------------------------------
// Stage 2c: k=12 patches, adaptive avg 12->8 (each output bin = mean of 2x2
// inputs at a=(3p)>>1, b=(3q)>>1). One thread = full 8-wide q row.
// ---------------------------------------------------------------------------
__global__ __launch_bounds__(256) void patch12_kernel(
    const float* __restrict__ y, float* __restrict__ out) {
  const unsigned idx = blockIdx.x * 256 + threadIdx.x;  // 3,936,256
  const int p = idx & 7;
  const int c = (idx >> 3) & 15;
  const unsigned rest = idx >> 7;       // n*L12 + l
  const int n = rest / L12;
  const int l = rest - n * L12;
  const int ow = l % 62, oh = l / 62;

  const int a = (3 * p) >> 1;           // padded row start of the 2-row bin
  const int r0 = min(max(oh * 4 + a - 1, 0), H - 1);
  const int r1 = min(max(oh * 4 + a, 0), H - 1);
  const int ws0 = ow * 4 - 1;
  const float* yb = y + (size_t)(n * C_OUT + c) * HW;
  const float* row0 = yb + (size_t)r0 * W;
  const float* row1 = yb + (size_t)r1 * W;

  const float4 t0 = load4c(row0, ws0), t1 = load4u(row0, ws0 + 4), t2 = load4u(row0, ws0 + 8);
  const float4 u0 = load4c(row1, ws0), u1 = load4u(row1, ws0 + 4), u2 = load4u(row1, ws0 + 8);
  const float tv[12] = {t0.x, t0.y, t0.z, t0.w, t1.x, t1.y, t1.z, t1.w, t2.x, t2.y, t2.z, t2.w};
  const float uv[12] = {u0.x, u0.y, u0.z, u0.w, u1.x, u1.y, u1.z, u1.w, u2.x, u2.y, u2.z, u2.w};

  const int bq[8] = {0, 1, 3, 4, 6, 7, 9, 10};
  float v[8];
#pragma unroll
  for (int q = 0; q < 8; ++q) {
    const int bb = bq[q];
    v[q] = 0.25f * (tv[bb] + tv[bb + 1] + uv[bb] + uv[bb + 1]);
  }

  float* op = out + ((size_t)(n * LTOT + L4 + L8 + l) * C_OUT + c) * 64 + p * 8;
  *reinterpret_cast<float4*>(op) = make_float4(v[0], v[1], v[2], v[3]);
  *reinterpret_cast<float4*>(op + 4) = make_float4(v[4], v[5], v[6], v[7]);
}

extern "C" void kernel_launch(void* const* d_in, const int* in_sizes, int n_in,
                              void* d_out, int out_size, void* d_ws, size_t ws_size,
                              hipStream_t stream) {
  const float* x = (const float*)d_in[0];
  const float* w = (const float*)d_in[1];
  const float* b = (const float*)d_in[2];
  float* out = (float*)d_out;
  float* y = (float*)d_ws;   // 8*16*256*256 floats = 33.5 MB (unpadded)

  reduce_kernel<<<512, 256, 0, stream>>>(x, w, b, y);
  patch4_kernel<<<(N_B * L4 * C_OUT * 8) / 256, 256, 0, stream>>>(y, out);   // 16384
  patch8_kernel<<<(N_B * L8 * C_OUT * 8) / 256, 256, 0, stream>>>(y, out);   // 15876
  patch12_kernel<<<(N_B * L12 * C_OUT * 8) / 256, 256, 0, stream>>>(y, out); // 15376
}

// Round 4
// 127.601 us; speedup vs baseline: 3.8862x; 1.9258x over previous
//
#include <hip/hip_runtime.h>

#define C_IN 64
#define C_OUT 16
#define H 256
#define W 256
#define HW 65536      // 256*256
#define N_B 8
#define L4 4096
#define L8 3969
#define L12 3844
#define LTOT 11909    // 4096 + 3969 + 3844
#define LDSP 260      // LDS row pitch in floats (256 data + 4 pad)

// 4-byte-aligned float4 for unaligned global row loads (col % 4 == 3)
typedef float float4u __attribute__((ext_vector_type(4), aligned(4)));
// native 16B vector for nontemporal stores
typedef float f4v __attribute__((ext_vector_type(4)));

__device__ __forceinline__ void nt_store4(const float4& v, float* p) {
  f4v t; t.x = v.x; t.y = v.y; t.z = v.z; t.w = v.w;
  __builtin_nontemporal_store(t, reinterpret_cast<f4v*>(p));
}

__device__ __forceinline__ float4 load4c(const float* __restrict__ row, int ws0) {
  if (ws0 >= 0) {
    float4u t = *reinterpret_cast<const float4u*>(row + ws0);
    return make_float4(t.x, t.y, t.z, t.w);
  }
  // ws0 == -1: padded cols {-1,0,1,2} -> clamp -1 -> 0
  return make_float4(row[0], row[0], row[1], row[2]);
}

// ---------------------------------------------------------------------------
// Stage 1: 1x1 conv 64->16 over the UNPADDED image (padding commutes with a
// 1x1 conv; patch kernels clamp coordinates instead). Each thread: 4 pixels
// (float4) x 16 outputs. Weights transposed in LDS, broadcast ds_read_b128.
// ---------------------------------------------------------------------------
__global__ __launch_bounds__(256) void reduce_kernel(
    const float* __restrict__ x, const float* __restrict__ w,
    const float* __restrict__ b, float* __restrict__ y) {
  __shared__ float wt[C_IN][C_OUT];   // wt[c][o]
  for (int i = threadIdx.x; i < C_IN * C_OUT; i += 256)
    wt[i & 63][i >> 6] = w[i];        // w flat = o*64 + c
  __syncthreads();

  const unsigned gid = blockIdx.x * 256 + threadIdx.x;  // 131072 total
  const int n = gid >> 14;
  const int pix = (gid & 16383) << 2;
  const float* xp = x + (size_t)n * C_IN * HW + pix;

  float4 acc[C_OUT];
#pragma unroll
  for (int o = 0; o < C_OUT; ++o) {
    const float bv = b[o];
    acc[o] = make_float4(bv, bv, bv, bv);
  }

#define FMA4(A, WS) \
  A.x = fmaf(xv.x, WS, A.x); A.y = fmaf(xv.y, WS, A.y); \
  A.z = fmaf(xv.z, WS, A.z); A.w = fmaf(xv.w, WS, A.w);

#pragma unroll
  for (int c = 0; c < C_IN; ++c) {
    const float4 xv = *reinterpret_cast<const float4*>(xp + (size_t)c * HW);
    const float4 w0 = *reinterpret_cast<const float4*>(&wt[c][0]);
    const float4 w1 = *reinterpret_cast<const float4*>(&wt[c][4]);
    const float4 w2 = *reinterpret_cast<const float4*>(&wt[c][8]);
    const float4 w3 = *reinterpret_cast<const float4*>(&wt[c][12]);
    FMA4(acc[0], w0.x)  FMA4(acc[1], w0.y)  FMA4(acc[2], w0.z)  FMA4(acc[3], w0.w)
    FMA4(acc[4], w1.x)  FMA4(acc[5], w1.y)  FMA4(acc[6], w1.z)  FMA4(acc[7], w1.w)
    FMA4(acc[8], w2.x)  FMA4(acc[9], w2.y)  FMA4(acc[10], w2.z) FMA4(acc[11], w2.w)
    FMA4(acc[12], w3.x) FMA4(acc[13], w3.y) FMA4(acc[14], w3.z) FMA4(acc[15], w3.w)
  }
#undef FMA4

  float* yp = y + (size_t)n * C_OUT * HW + pix;
#pragma unroll
  for (int o = 0; o < C_OUT; ++o)
    *reinterpret_cast<float4*>(yp + (size_t)o * HW) = acc[o];
}

// ---------------------------------------------------------------------------
// LDS-tiled patch kernels. Block = (n, cq, oh). Stage the shifted padded
// tile lds[c][t][j] = y[clamp(oh*4+t-1)][clamp(j-1)] so all compute reads
// are 16B-aligned ds_read_b128. Lane = (c:2, p:3, qh:1) -> wave writes 1KB
// contiguous out. Waves (tid>>6) cover ow = i*4 + (tid>>6).
// ---------------------------------------------------------------------------

// ---- k=4: bilinear 4x4 -> 8x8 ----
__global__ __launch_bounds__(256) void patch4_kernel(
    const float* __restrict__ y, float* __restrict__ out) {
  const int CP = 4 * LDSP + 8;
  __shared__ float lds[4 * (4 * LDSP + 8)];
  const int bid = blockIdx.x;
  const int oh = bid & 63;
  const int cq = (bid >> 6) & 3;
  const int n = bid >> 8;
  const int tid = threadIdx.x;

#pragma unroll
  for (int i = 0; i < 4; ++i) {
    const int sid = i * 256 + tid;
    const int c = sid >> 8;
    const int t = (sid >> 6) & 3;
    const int k = sid & 63;
    const int r = min(max(oh * 4 + t - 1, 0), H - 1);
    const float4 v = load4c(y + (size_t)(n * C_OUT + cq * 4 + c) * HW + (size_t)r * W, 4 * k - 1);
    *reinterpret_cast<float4*>(&lds[c * CP + t * LDSP + 4 * k]) = v;
  }
  __syncthreads();

  const int lane = tid & 63;
  const int c = lane >> 4;
  const int p = (lane >> 1) & 7;
  const int qh = lane & 1;
  const int lrow = tid >> 6;

  const int ip0 = max(0, (p - 1) >> 1), ip1 = min(3, (p + 1) >> 1);
  const float wp0 = (p == 0 || p == 7) ? 1.0f : ((p & 1) ? 0.75f : 0.25f);
  const float wp1 = 1.0f - wp0;
  const float* lr0 = &lds[c * CP + ip0 * LDSP];
  const float* lr1 = &lds[c * CP + ip1 * LDSP];
  float* ob = out + ((size_t)(n * LTOT + oh * 64) * C_OUT + cq * 4 + c) * 64 + p * 8 + qh * 4;

#pragma unroll
  for (int i = 0; i < 16; ++i) {
    const int ow = i * 4 + lrow;
    const float4 A = *reinterpret_cast<const float4*>(lr0 + ow * 4);
    const float4 B = *reinterpret_cast<const float4*>(lr1 + ow * 4);
    float4 ta, tb;
    if (qh == 0) {
      ta = make_float4(A.x, 0.75f * A.x + 0.25f * A.y, 0.25f * A.x + 0.75f * A.y, 0.75f * A.y + 0.25f * A.z);
      tb = make_float4(B.x, 0.75f * B.x + 0.25f * B.y, 0.25f * B.x + 0.75f * B.y, 0.75f * B.y + 0.25f * B.z);
    } else {
      ta = make_float4(0.25f * A.y + 0.75f * A.z, 0.75f * A.z + 0.25f * A.w, 0.25f * A.z + 0.75f * A.w, A.w);
      tb = make_float4(0.25f * B.y + 0.75f * B.z, 0.75f * B.z + 0.25f * B.w, 0.25f * B.z + 0.75f * B.w, B.w);
    }
    const float4 v = make_float4(wp0 * ta.x + wp1 * tb.x, wp0 * ta.y + wp1 * tb.y,
                                 wp0 * ta.z + wp1 * tb.z, wp0 * ta.w + wp1 * tb.w);
    nt_store4(v, ob + (size_t)ow * (C_OUT * 64));
  }
}

// ---- k=8: identity copy ----
__global__ __launch_bounds__(256) void patch8_kernel(
    const float* __restrict__ y, float* __restrict__ out) {
  const int CP = 8 * LDSP + 8;
  __shared__ float lds[4 * (8 * LDSP + 8)];
  const int bid = blockIdx.x;
  const int oh = bid % 63;
  const int cqn = bid / 63;
  const int cq = cqn & 3;
  const int n = cqn >> 2;
  const int tid = threadIdx.x;

#pragma unroll
  for (int i = 0; i < 8; ++i) {
    const int sid = i * 256 + tid;
    const int c = sid >> 9;
    const int t = (sid >> 6) & 7;
    const int k = sid & 63;
    const int r = min(max(oh * 4 + t - 1, 0), H - 1);
    const float4 v = load4c(y + (size_t)(n * C_OUT + cq * 4 + c) * HW + (size_t)r * W, 4 * k - 1);
    *reinterpret_cast<float4*>(&lds[c * CP + t * LDSP + 4 * k]) = v;
  }
  __syncthreads();

  const int lane = tid & 63;
  const int c = lane >> 4;
  const int p = (lane >> 1) & 7;
  const int qh = lane & 1;
  const int lrow = tid >> 6;

  const float* lr = &lds[c * CP + p * LDSP + qh * 4];
  float* ob = out + ((size_t)(n * LTOT + L4 + oh * 63) * C_OUT + cq * 4 + c) * 64 + p * 8 + qh * 4;

#pragma unroll
  for (int i = 0; i < 16; ++i) {
    const int ow = i * 4 + lrow;
    if (ow < 63) {
      const float4 v = *reinterpret_cast<const float4*>(lr + ow * 4);
      nt_store4(v, ob + (size_t)ow * (C_OUT * 64));
    }
  }
}

// ---- k=12: adaptive avg 12 -> 8 (2x2 mean at a=(3p)>>1, b=(3q)>>1) ----
__global__ __launch_bounds__(256) void patch12_kernel(
    const float* __restrict__ y, float* __restrict__ out) {
  const int CP = 12 * LDSP + 8;
  __shared__ float lds[4 * (12 * LDSP + 8)];
  const int bid = blockIdx.x;
  const int oh = bid % 62;
  const int cqn = bid / 62;
  const int cq = cqn & 3;
  const int n = cqn >> 2;
  const int tid = threadIdx.x;

#pragma unroll
  for (int i = 0; i < 12; ++i) {
    const int sid = i * 256 + tid;
    const int c = sid / 768;
    const int rem = sid - c * 768;
    const int t = rem >> 6;
    const int k = rem & 63;
    const int r = min(max(oh * 4 + t - 1, 0), H - 1);
    const float4 v = load4c(y + (size_t)(n * C_OUT + cq * 4 + c) * HW + (size_t)r * W, 4 * k - 1);
    *reinterpret_cast<float4*>(&lds[c * CP + t * LDSP + 4 * k]) = v;
  }
  __syncthreads();

  const int lane = tid & 63;
  const int c = lane >> 4;
  const int p = (lane >> 1) & 7;
  const int qh = lane & 1;
  const int lrow = tid >> 6;

  const int a = (3 * p) >> 1;               // tile row of the 2-row bin
  const float* r0 = &lds[c * CP + a * LDSP];
  const float* r1 = r0 + LDSP;
  float* ob = out + ((size_t)(n * LTOT + L4 + L8 + oh * 62) * C_OUT + cq * 4 + c) * 64 + p * 8 + qh * 4;

#pragma unroll
  for (int i = 0; i < 16; ++i) {
    const int ow = i * 4 + lrow;
    if (ow < 62) {
      // need local cols qh*6 .. qh*6+5 of the 12-col window at ow*4.
      // uniform pattern: F4 = b128 at ow*4 + qh*8, F2 = b64 at ow*4 + 4 + qh*2
      const float4 F40 = *reinterpret_cast<const float4*>(r0 + ow * 4 + qh * 8);
      const float2 F20 = *reinterpret_cast<const float2*>(r0 + ow * 4 + 4 + qh * 2);
      const float4 F41 = *reinterpret_cast<const float4*>(r1 + ow * 4 + qh * 8);
      const float2 F21 = *reinterpret_cast<const float2*>(r1 + ow * 4 + 4 + qh * 2);
      // local e[0..5]: qh0 -> {F4.xyzw, F2.xy}; qh1 -> {F2.xy, F4.xyzw}
      const float e0 = qh ? F20.x : F40.x, f0 = qh ? F21.x : F41.x;
      const float e1 = qh ? F20.y : F40.y, f1 = qh ? F21.y : F41.y;
      const float e2 = qh ? F40.x : F40.z, f2 = qh ? F41.x : F41.z;
      const float e3 = qh ? F40.y : F40.w, f3 = qh ? F41.y : F41.w;
      const float e4 = qh ? F40.z : F20.x, f4 = qh ? F41.z : F21.x;
      const float e5 = qh ? F40.w : F20.y, f5 = qh ? F41.w : F21.y;
      // output j uses local cols bb,bb+1 with bb = {0,1,3,4}
      const float4 v = make_float4(0.25f * (e0 + e1 + f0 + f1),
                                   0.25f * (e1 + e2 + f1 + f2),
                                   0.25f * (e3 + e4 + f3 + f4),
                                   0.25f * (e4 + e5 + f4 + f5));
      nt_store4(v, ob + (size_t)ow * (C_OUT * 64));
    }
  }
}

extern "C" void kernel_launch(void* const* d_in, const int* in_sizes, int n_in,
                              void* d_out, int out_size, void* d_ws, size_t ws_size,
                              hipStream_t stream) {
  const float* x = (const float*)d_in[0];
  const float* w = (const float*)d_in[1];
  const float* b = (const float*)d_in[2];
  float* out = (float*)d_out;
  float* y = (float*)d_ws;   // 8*16*256*256 floats = 33.5 MB

  reduce_kernel<<<512, 256, 0, stream>>>(x, w, b, y);
  patch4_kernel<<<N_B * 4 * 64, 256, 0, stream>>>(y, out);   // 2048 blocks
  patch8_kernel<<<N_B * 4 * 63, 256, 0, stream>>>(y, out);   // 2016 blocks
  patch12_kernel<<<N_B * 4 * 62, 256, 0, stream>>>(y, out);  // 1984 blocks
}

// Round 5
// 109.373 us; speedup vs baseline: 4.5338x; 1.1667x over previous
//
#include <hip/hip_runtime.h>

#define C_IN 64
#define C_OUT 16
#define H 256
#define W 256
#define HW 65536      // 256*256
#define N_B 8
#define L4 4096
#define L8 3969
#define L12 3844
#define LTOT 11909    // 4096 + 3969 + 3844
#define LDSP 260      // LDS row pitch in floats (256 data + 4 pad)

// 4-byte-aligned float4 for unaligned global row loads (col % 4 == 3)
typedef float float4u __attribute__((ext_vector_type(4), aligned(4)));
// native 16B vector for nontemporal stores
typedef float f4v __attribute__((ext_vector_type(4)));

__device__ __forceinline__ void nt_store4(const float4& v, float* p) {
  f4v t; t.x = v.x; t.y = v.y; t.z = v.z; t.w = v.w;
  __builtin_nontemporal_store(t, reinterpret_cast<f4v*>(p));
}

__device__ __forceinline__ float4 load4c(const float* __restrict__ row, int ws0) {
  if (ws0 >= 0) {
    float4u t = *reinterpret_cast<const float4u*>(row + ws0);
    return make_float4(t.x, t.y, t.z, t.w);
  }
  // ws0 == -1: padded cols {-1,0,1,2} -> clamp -1 -> 0
  return make_float4(row[0], row[0], row[1], row[2]);
}

// ---------------------------------------------------------------------------
// Stage 1: 1x1 conv 64->16 over the UNPADDED image (padding commutes with a
// 1x1 conv; the patch kernel clamps coordinates instead). Each thread: 4
// pixels (float4) x 16 outputs. Weights transposed in LDS, broadcast b128.
// y stores are NORMAL (not nontemporal): stage 2 re-reads y via L2/L3.
// ---------------------------------------------------------------------------
__global__ __launch_bounds__(256) void reduce_kernel(
    const float* __restrict__ x, const float* __restrict__ w,
    const float* __restrict__ b, float* __restrict__ y) {
  __shared__ float wt[C_IN][C_OUT];   // wt[c][o]
  for (int i = threadIdx.x; i < C_IN * C_OUT; i += 256)
    wt[i & 63][i >> 6] = w[i];        // w flat = o*64 + c
  __syncthreads();

  const unsigned gid = blockIdx.x * 256 + threadIdx.x;  // 131072 total
  const int n = gid >> 14;
  const int pix = (gid & 16383) << 2;
  const float* xp = x + (size_t)n * C_IN * HW + pix;

  float4 acc[C_OUT];
#pragma unroll
  for (int o = 0; o < C_OUT; ++o) {
    const float bv = b[o];
    acc[o] = make_float4(bv, bv, bv, bv);
  }

#define FMA4(A, WS) \
  A.x = fmaf(xv.x, WS, A.x); A.y = fmaf(xv.y, WS, A.y); \
  A.z = fmaf(xv.z, WS, A.z); A.w = fmaf(xv.w, WS, A.w);

#pragma unroll
  for (int c = 0; c < C_IN; ++c) {
    const float4 xv = *reinterpret_cast<const float4*>(xp + (size_t)c * HW);
    const float4 w0 = *reinterpret_cast<const float4*>(&wt[c][0]);
    const float4 w1 = *reinterpret_cast<const float4*>(&wt[c][4]);
    const float4 w2 = *reinterpret_cast<const float4*>(&wt[c][8]);
    const float4 w3 = *reinterpret_cast<const float4*>(&wt[c][12]);
    FMA4(acc[0], w0.x)  FMA4(acc[1], w0.y)  FMA4(acc[2], w0.z)  FMA4(acc[3], w0.w)
    FMA4(acc[4], w1.x)  FMA4(acc[5], w1.y)  FMA4(acc[6], w1.z)  FMA4(acc[7], w1.w)
    FMA4(acc[8], w2.x)  FMA4(acc[9], w2.y)  FMA4(acc[10], w2.z) FMA4(acc[11], w2.w)
    FMA4(acc[12], w3.x) FMA4(acc[13], w3.y) FMA4(acc[14], w3.z) FMA4(acc[15], w3.w)
  }
#undef FMA4

  float* yp = y + (size_t)n * C_OUT * HW + pix;
#pragma unroll
  for (int o = 0; o < C_OUT; ++o)
    *reinterpret_cast<float4*>(yp + (size_t)o * HW) = acc[o];
}

// ---------------------------------------------------------------------------
// Stage 2 (FUSED): one kernel emits all three branches from ONE staged tile.
// Block = (n, cq, oh in 0..63). Stage 12 clamp-padded rows x 4 channels:
//   lds[c][t][j] = y[clamp(oh*4+t-1)][clamp(j-1)]   (16B-aligned b128 reads)
// Then: branch4 (bilinear 4x4->8x8, rows t0..t3, always),
//       branch8 (copy, rows t0..t7, if oh<63),
//       branch12 (adaptive avg 12->8, rows t0..t11, if oh<62).
// Lane = (c:2, p:3, qh:1) -> each wave's store covers 1KB contiguous out.
// ---------------------------------------------------------------------------
__global__ __launch_bounds__(256) void patch_fused_kernel(
    const float* __restrict__ y, float* __restrict__ out) {
  const int CP = 12 * LDSP + 8;
  __shared__ float lds[4 * (12 * LDSP + 8)];   // 50,048 B
  const int bid = blockIdx.x;
  const int oh = bid & 63;
  const int cq = (bid >> 6) & 3;
  const int n = bid >> 8;
  const int tid = threadIdx.x;

  // ---- staging: 12 x 256 threads cover (c:4, t:12, k:64) ----
#pragma unroll
  for (int i = 0; i < 12; ++i) {
    const int sid = i * 256 + tid;
    const int c = sid / 768;
    const int rem = sid - c * 768;
    const int t = rem >> 6;
    const int k = rem & 63;
    const int r = min(max(oh * 4 + t - 1, 0), H - 1);
    const float4 v = load4c(y + (size_t)(n * C_OUT + cq * 4 + c) * HW + (size_t)r * W, 4 * k - 1);
    *reinterpret_cast<float4*>(&lds[c * CP + t * LDSP + 4 * k]) = v;
  }
  __syncthreads();

  const int lane = tid & 63;
  const int c = lane >> 4;
  const int p = (lane >> 1) & 7;
  const int qh = lane & 1;
  const int lrow = tid >> 6;
  const float* lc = &lds[c * CP];
  const size_t obase = ((size_t)n * LTOT) * (C_OUT * 64) + (size_t)(cq * 4 + c) * 64 + p * 8 + qh * 4;

  // ---- branch 4: bilinear 4x4 -> 8x8 ----
  {
    const int ip0 = max(0, (p - 1) >> 1), ip1 = min(3, (p + 1) >> 1);
    const float wp0 = (p == 0 || p == 7) ? 1.0f : ((p & 1) ? 0.75f : 0.25f);
    const float wp1 = 1.0f - wp0;
    const float* lr0 = lc + ip0 * LDSP;
    const float* lr1 = lc + ip1 * LDSP;
    float* ob = out + obase + (size_t)(oh * 64) * (C_OUT * 64);

#pragma unroll
    for (int i = 0; i < 16; ++i) {
      const int ow = i * 4 + lrow;
      const float4 A = *reinterpret_cast<const float4*>(lr0 + ow * 4);
      const float4 B = *reinterpret_cast<const float4*>(lr1 + ow * 4);
      float4 ta, tb;
      if (qh == 0) {
        ta = make_float4(A.x, 0.75f * A.x + 0.25f * A.y, 0.25f * A.x + 0.75f * A.y, 0.75f * A.y + 0.25f * A.z);
        tb = make_float4(B.x, 0.75f * B.x + 0.25f * B.y, 0.25f * B.x + 0.75f * B.y, 0.75f * B.y + 0.25f * B.z);
      } else {
        ta = make_float4(0.25f * A.y + 0.75f * A.z, 0.75f * A.z + 0.25f * A.w, 0.25f * A.z + 0.75f * A.w, A.w);
        tb = make_float4(0.25f * B.y + 0.75f * B.z, 0.75f * B.z + 0.25f * B.w, 0.25f * B.z + 0.75f * B.w, B.w);
      }
      const float4 v = make_float4(wp0 * ta.x + wp1 * tb.x, wp0 * ta.y + wp1 * tb.y,
                                   wp0 * ta.z + wp1 * tb.z, wp0 * ta.w + wp1 * tb.w);
      nt_store4(v, ob + (size_t)ow * (C_OUT * 64));
    }
  }

  // ---- branch 8: identity copy ----
  if (oh < 63) {
    const float* lr = lc + p * LDSP + qh * 4;
    float* ob = out + obase + (size_t)(L4 + oh * 63) * (C_OUT * 64);
#pragma unroll
    for (int i = 0; i < 16; ++i) {
      const int ow = i * 4 + lrow;
      if (ow < 63) {
        const float4 v = *reinterpret_cast<const float4*>(lr + ow * 4);
        nt_store4(v, ob + (size_t)ow * (C_OUT * 64));
      }
    }
  }

  // ---- branch 12: adaptive avg 12 -> 8 (2x2 mean at a=(3p)>>1, b=(3q)>>1) ----
  if (oh < 62) {
    const int a = (3 * p) >> 1;
    const float* r0 = lc + a * LDSP;
    const float* r1 = r0 + LDSP;
    float* ob = out + obase + (size_t)(L4 + L8 + oh * 62) * (C_OUT * 64);
#pragma unroll
    for (int i = 0; i < 16; ++i) {
      const int ow = i * 4 + lrow;
      if (ow < 62) {
        // local cols qh*6..qh*6+5 of the 12-col window at ow*4:
        // F4 = b128 at ow*4 + qh*8, F2 = b64 at ow*4 + 4 + qh*2
        const float4 F40 = *reinterpret_cast<const float4*>(r0 + ow * 4 + qh * 8);
        const float2 F20 = *reinterpret_cast<const float2*>(r0 + ow * 4 + 4 + qh * 2);
        const float4 F41 = *reinterpret_cast<const float4*>(r1 + ow * 4 + qh * 8);
        const float2 F21 = *reinterpret_cast<const float2*>(r1 + ow * 4 + 4 + qh * 2);
        const float e0 = qh ? F20.x : F40.x, f0 = qh ? F21.x : F41.x;
        const float e1 = qh ? F20.y : F40.y, f1 = qh ? F21.y : F41.y;
        const float e2 = qh ? F40.x : F40.z, f2 = qh ? F41.x : F41.z;
        const float e3 = qh ? F40.y : F40.w, f3 = qh ? F41.y : F41.w;
        const float e4 = qh ? F40.z : F20.x, f4 = qh ? F41.z : F21.x;
        const float e5 = qh ? F40.w : F20.y, f5 = qh ? F41.w : F21.y;
        const float4 v = make_float4(0.25f * (e0 + e1 + f0 + f1),
                                     0.25f * (e1 + e2 + f1 + f2),
                                     0.25f * (e3 + e4 + f3 + f4),
                                     0.25f * (e4 + e5 + f4 + f5));
        nt_store4(v, ob + (size_t)ow * (C_OUT * 64));
      }
    }
  }
}

extern "C" void kernel_launch(void* const* d_in, const int* in_sizes, int n_in,
                              void* d_out, int out_size, void* d_ws, size_t ws_size,
                              hipStream_t stream) {
  const float* x = (const float*)d_in[0];
  const float* w = (const float*)d_in[1];
  const float* b = (const float*)d_in[2];
  float* out = (float*)d_out;
  float* y = (float*)d_ws;   // 8*16*256*256 floats = 33.5 MB

  reduce_kernel<<<512, 256, 0, stream>>>(x, w, b, y);
  patch_fused_kernel<<<N_B * 4 * 64, 256, 0, stream>>>(y, out);  // 2048 blocks
}